// Round 3
// baseline (4050.726 us; speedup 1.0000x reference)
//
#include <hip/hip_runtime.h>
#include <hip/hip_bf16.h>

#define B_   32
#define L_   1024
#define DIN_ 9
#define DM_  512
#define NL_  4
#define DI_  1024
#define DS_  16
#define DC_  4
#define DTR_ 32
#define NC_  12
#define M_   (B_*L_)

typedef unsigned short u16;
typedef __attribute__((ext_vector_type(8))) short bf16x8;
typedef __attribute__((ext_vector_type(4))) float f32x4;

__device__ __forceinline__ float bf2f(u16 h){
  union { unsigned int u; float f; } v; v.u = ((unsigned int)h) << 16; return v.f;
}
__device__ __forceinline__ u16 f2bf(float f){
  union { float f; unsigned int u; } v; v.f = f;
  unsigned int u = v.u;
  return (u16)((u + 0x7fffu + ((u >> 16) & 1u)) >> 16);
}

// ---------------- input projection: h = bf16(x @ ip_w^T + ip_b) ----------------
__global__ __launch_bounds__(512) void inproj_kernel(const float* __restrict__ x,
                                                     const float* __restrict__ w,
                                                     const float* __restrict__ bias,
                                                     u16* __restrict__ h){
  int m = blockIdx.x;          // 0..32767
  int d = threadIdx.x;         // 0..511
  __shared__ float xr[DIN_];
  if (threadIdx.x < DIN_) xr[threadIdx.x] = x[(size_t)m * DIN_ + threadIdx.x];
  __syncthreads();
  float a = bias[d];
#pragma unroll
  for (int i = 0; i < DIN_; i++) a += xr[i] * w[d * DIN_ + i];
  h[(size_t)m * DM_ + d] = f2bf(a);
}

// ---------------- layernorm: bf16 h -> bf16 hn ----------------
__global__ __launch_bounds__(256) void ln_kernel(const u16* __restrict__ h,
                                                 const float* __restrict__ g,
                                                 const float* __restrict__ bt,
                                                 u16* __restrict__ hn){
  int row = blockIdx.x * 4 + (threadIdx.x >> 6);
  int lane = threadIdx.x & 63;
  const u16* hr = h + (size_t)row * DM_ + lane * 8;
  ushort4 a0 = *(const ushort4*)(hr);
  ushort4 a1 = *(const ushort4*)(hr + 4);
  float v[8];
  v[0]=bf2f(a0.x); v[1]=bf2f(a0.y); v[2]=bf2f(a0.z); v[3]=bf2f(a0.w);
  v[4]=bf2f(a1.x); v[5]=bf2f(a1.y); v[6]=bf2f(a1.z); v[7]=bf2f(a1.w);
  float s = 0.f, q = 0.f;
#pragma unroll
  for (int i = 0; i < 8; i++){ s += v[i]; q += v[i]*v[i]; }
#pragma unroll
  for (int o = 32; o; o >>= 1){ s += __shfl_xor(s, o); q += __shfl_xor(q, o); }
  float mean = s * (1.f / DM_);
  float rstd = rsqrtf(q * (1.f / DM_) - mean * mean + 1e-5f);
  float4 g0 = *(const float4*)(g + lane * 8);
  float4 g1 = *(const float4*)(g + lane * 8 + 4);
  float4 b0 = *(const float4*)(bt + lane * 8);
  float4 b1 = *(const float4*)(bt + lane * 8 + 4);
  ushort4 o0, o1;
  o0.x = f2bf((v[0]-mean)*rstd*g0.x + b0.x);
  o0.y = f2bf((v[1]-mean)*rstd*g0.y + b0.y);
  o0.z = f2bf((v[2]-mean)*rstd*g0.z + b0.z);
  o0.w = f2bf((v[3]-mean)*rstd*g0.w + b0.w);
  o1.x = f2bf((v[4]-mean)*rstd*g1.x + b1.x);
  o1.y = f2bf((v[5]-mean)*rstd*g1.y + b1.y);
  o1.z = f2bf((v[6]-mean)*rstd*g1.z + b1.z);
  o1.w = f2bf((v[7]-mean)*rstd*g1.w + b1.w);
  u16* op = hn + (size_t)row * DM_ + lane * 8;
  *(ushort4*)(op)     = o0;
  *(ushort4*)(op + 4) = o1;
}

// ---------------- GEMM: C[M][N] = A[M][K] (bf16) @ W[N][K]^T (fp32->bf16 on the fly) --
// EPI 0: store bf16. EPI 1: bf16(softplus(v + bias[n])). EPI 2: bf16(v + Res) residual
// (Cb may alias Res). EPI 4: split output: n<nsplit -> Cb (raw), else Cb2 (silu), both
// with row stride nsplit.
template<int BM, int BN, int BK, int EPI>
__global__ __launch_bounds__(256)
void gemm_bt(const u16* __restrict__ A, int lda,
             const float* __restrict__ Bw,
             u16* Cb, u16* Cb2, const float* __restrict__ bias,
             const u16* Res, int N, int K, int nsplit){
  constexpr int CH = BK / 8;
  constexpr int MASK = CH - 1;
  constexpr int WM = BM / 2, WN = BN / 2;
  constexpr int FM = WM / 16, FN = WN / 16;
  __shared__ u16 As[BM * BK];
  __shared__ u16 Bs[BN * BK];
  const int tid = threadIdx.x;
  const int lane = tid & 63;
  const int wid = tid >> 6;
  const int wr = wid >> 1, wc = wid & 1;
  const int bm = blockIdx.y * BM, bn = blockIdx.x * BN;
  f32x4 acc[FM][FN];
#pragma unroll
  for (int i = 0; i < FM; i++)
#pragma unroll
    for (int j = 0; j < FN; j++) acc[i][j] = f32x4{0.f, 0.f, 0.f, 0.f};
  constexpr int LA = BM * BK / (256 * 8);
  constexpr int LB = BN * BK / (256 * 8);
  for (int k0 = 0; k0 < K; k0 += BK){
    __syncthreads();
#pragma unroll
    for (int i = 0; i < LA; i++){
      int chunk = i * 256 + tid;
      int row = chunk / CH, cc = chunk & MASK;
      uint4 v = *(const uint4*)(A + (size_t)(bm + row) * lda + k0 + cc * 8);
      *(uint4*)(&As[row * BK + ((cc ^ (row & MASK))) * 8]) = v;
    }
#pragma unroll
    for (int i = 0; i < LB; i++){
      int chunk = i * 256 + tid;
      int row = chunk / CH, cc = chunk & MASK;
      const float* bp = Bw + (size_t)(bn + row) * K + k0 + cc * 8;
      float4 f0 = *(const float4*)(bp);
      float4 f1 = *(const float4*)(bp + 4);
      ushort4 h0, h1;
      h0.x = f2bf(f0.x); h0.y = f2bf(f0.y); h0.z = f2bf(f0.z); h0.w = f2bf(f0.w);
      h1.x = f2bf(f1.x); h1.y = f2bf(f1.y); h1.z = f2bf(f1.z); h1.w = f2bf(f1.w);
      u16* dst = &Bs[row * BK + ((cc ^ (row & MASK))) * 8];
      *(ushort4*)(dst)     = h0;
      *(ushort4*)(dst + 4) = h1;
    }
    __syncthreads();
#pragma unroll
    for (int kk = 0; kk < BK / 32; kk++){
      bf16x8 af[FM], bfr[FN];
      const int kch = kk * 4 + (lane >> 4);
#pragma unroll
      for (int mi = 0; mi < FM; mi++){
        int r = wr * WM + mi * 16 + (lane & 15);
        af[mi] = *(const bf16x8*)(&As[r * BK + ((kch ^ (r & MASK))) * 8]);
      }
#pragma unroll
      for (int ni = 0; ni < FN; ni++){
        int r = wc * WN + ni * 16 + (lane & 15);
        bfr[ni] = *(const bf16x8*)(&Bs[r * BK + ((kch ^ (r & MASK))) * 8]);
      }
#pragma unroll
      for (int mi = 0; mi < FM; mi++)
#pragma unroll
        for (int ni = 0; ni < FN; ni++)
          acc[mi][ni] = __builtin_amdgcn_mfma_f32_16x16x32_bf16(af[mi], bfr[ni], acc[mi][ni], 0, 0, 0);
    }
  }
  const int rq = (lane >> 4) * 4, cl = lane & 15;
#pragma unroll
  for (int mi = 0; mi < FM; mi++){
#pragma unroll
    for (int ni = 0; ni < FN; ni++){
      const int n = bn + wc * WN + ni * 16 + cl;
#pragma unroll
      for (int j = 0; j < 4; j++){
        const int m = bm + wr * WM + mi * 16 + rq + j;
        float v = acc[mi][ni][j];
        if constexpr (EPI == 0){
          Cb[(size_t)m * N + n] = f2bf(v);
        } else if constexpr (EPI == 1){
          float xx = v + bias[n];
          float sp = (xx > 20.f) ? xx : log1pf(__expf(xx));
          Cb[(size_t)m * N + n] = f2bf(sp);
        } else if constexpr (EPI == 2){
          const size_t off = (size_t)m * N + n;
          Cb[off] = f2bf(v + bf2f(Res[off]));
        } else {
          if (n < nsplit){
            Cb[(size_t)m * nsplit + n] = f2bf(v);
          } else {
            float sg = v / (1.f + __expf(-v));
            Cb2[(size_t)m * nsplit + (n - nsplit)] = f2bf(sg);
          }
        }
      }
    }
  }
}

// ---------------- causal depthwise conv (DC=4) + SiLU ----------------
__global__ __launch_bounds__(256) void conv_kernel(const u16* __restrict__ xu,
                                                   const float* __restrict__ cw,
                                                   const float* __restrict__ cb,
                                                   u16* __restrict__ u){
  int idx = blockIdx.x * 256 + threadIdx.x;        // over Mc*DI
  int e = idx & (DI_ - 1);
  int bl = idx >> 10;
  int l = bl & (L_ - 1);
  const u16* p = xu + (size_t)bl * DI_ + e;
  float w0 = cw[e * 4 + 0], w1 = cw[e * 4 + 1], w2 = cw[e * 4 + 2], w3 = cw[e * 4 + 3];
  float a = cb[e];
  a += bf2f(p[0]) * w3;
  if (l >= 1) a += bf2f(*(p - DI_)) * w2;
  if (l >= 2) a += bf2f(*(p - 2 * DI_)) * w1;
  if (l >= 3) a += bf2f(*(p - 3 * DI_)) * w0;
  float sg = a / (1.f + __expf(-a));
  u[idx] = f2bf(sg);
}

// ---------------- selective scan + fused gate (in-place over delta) ----------------
__global__ __launch_bounds__(256)
void scan_kernel(u16* __restrict__ du,            // in: softplus'd delta; out: gated y
                 const u16* __restrict__ u,       // (Bc,L,DI) bf16
                 const u16* __restrict__ xdbl,    // (Bc,L,64) bf16 (cols 32..63 = B,C)
                 const u16* __restrict__ zs,      // silu(z) (Bc,L,DI) bf16
                 const float* __restrict__ A_log, // (DI,DS)
                 const float* __restrict__ Dp){   // (DI)
  const int b = blockIdx.y;
  const int e = blockIdx.x * 256 + threadIdx.x;
  const int tid = threadIdx.x;
  float As[DS_];
#pragma unroll
  for (int s = 0; s < DS_; s++) As[s] = -__expf(A_log[e * DS_ + s]);
  const float Dv = Dp[e];
  float h[DS_];
#pragma unroll
  for (int s = 0; s < DS_; s++) h[s] = 0.f;
  __shared__ float BC[16][32];
  const size_t base = (size_t)b * L_ * DI_ + e;
  const size_t xbase = (size_t)b * L_ * 64;
  for (int l0 = 0; l0 < L_; l0 += 16){
    __syncthreads();
    {
      int row = tid >> 4, c2 = (tid & 15) * 2;
      unsigned int v = *(const unsigned int*)(xdbl + xbase + (size_t)(l0 + row) * 64 + 32 + c2);
      BC[row][c2]     = bf2f((u16)(v & 0xffffu));
      BC[row][c2 + 1] = bf2f((u16)(v >> 16));
    }
    __syncthreads();
#pragma unroll 2
    for (int j = 0; j < 16; j++){
      const size_t idx = base + (size_t)(l0 + j) * DI_;
      float dd = bf2f(du[idx]);
      float uu = bf2f(u[idx]);
      float du_ = dd * uu;
      float yv = 0.f;
#pragma unroll
      for (int s = 0; s < DS_; s++){
        float dA = __expf(dd * As[s]);
        h[s] = dA * h[s] + du_ * BC[j][s];
        yv += h[s] * BC[j][16 + s];
      }
      float zv = bf2f(zs[idx]);
      du[idx] = f2bf((yv + uu * Dv) * zv);
    }
  }
}

// ---------------- mean-pool partials over L (bf16 h) ----------------
__global__ __launch_bounds__(256) void pool_kernel(const u16* __restrict__ h,
                                                   float* __restrict__ part){
  int d = blockIdx.x * 256 + threadIdx.x;  // 0..511 (2 blocks)
  int b = blockIdx.y;
  int p = blockIdx.z;                      // 8 chunks of 128
  float s = 0.f;
  const u16* hp = h + ((size_t)b * L_ + p * 128) * DM_ + d;
  for (int l = 0; l < 128; l++) s += bf2f(hp[(size_t)l * DM_]);
  part[((size_t)p * B_ + b) * DM_ + d] = s;
}

// ---------------- final FC ----------------
__global__ __launch_bounds__(256) void fc_kernel(const float* __restrict__ part,
                                                 const float* __restrict__ fcw,
                                                 const float* __restrict__ fcb,
                                                 float* __restrict__ out){
  int b = blockIdx.x;
  int tid = threadIdx.x;
  __shared__ float pd[DM_];
  for (int d = tid; d < DM_; d += 256){
    float s = 0.f;
    for (int p = 0; p < 8; p++) s += part[((size_t)p * B_ + b) * DM_ + d];
    pd[d] = s * (1.f / L_);
  }
  __syncthreads();
  int wid = tid >> 6, lane = tid & 63;
  for (int c = wid; c < NC_; c += 4){
    float s = 0.f;
    for (int d = lane; d < DM_; d += 64) s += pd[d] * fcw[c * DM_ + d];
#pragma unroll
    for (int o = 32; o; o >>= 1) s += __shfl_xor(s, o);
    if (lane == 0) out[b * NC_ + c] = s + fcb[c];
  }
}

extern "C" void kernel_launch(void* const* d_in, const int* in_sizes, int n_in,
                              void* d_out, int out_size, void* d_ws, size_t ws_size,
                              hipStream_t stream){
  const float* x     = (const float*)d_in[0];
  const float* ip_w  = (const float*)d_in[1];
  const float* ip_b  = (const float*)d_in[2];
  const float* ln_g  = (const float*)d_in[3];
  const float* ln_b  = (const float*)d_in[4];
  const float* inpw  = (const float*)d_in[5];
  const float* convw = (const float*)d_in[6];
  const float* convb = (const float*)d_in[7];
  const float* xpw   = (const float*)d_in[8];
  const float* dtw   = (const float*)d_in[9];
  const float* dtb   = (const float*)d_in[10];
  const float* Alog  = (const float*)d_in[11];
  const float* Dp    = (const float*)d_in[12];
  const float* outw  = (const float*)d_in[13];
  const float* fcw   = (const float*)d_in[14];
  const float* fcb   = (const float*)d_in[15];
  float* out = (float*)d_out;

  char* ws = (char*)d_ws;
  size_t off = 0;
  auto alloc = [&](size_t bytes) -> void* {
    void* p = ws + off; off += (bytes + 255) & ~(size_t)255; return p;
  };
  // ---- persistent (~32.5 MB): residual h (bf16) + pool partials ----
  u16*   h16  = (u16*)  alloc((size_t)M_ * DM_ * 2);            // 32 MB
  float* part = (float*)alloc((size_t)8 * B_ * DM_ * 4);        // 0.5 MB

  // ---- choose batch-chunking so per-chunk buffers fit ws_size ----
  // per-chunk bytes = Mc*2048 (X: hn then u) + Mc*2048 (xu/dlt/y) + Mc*2048 (silu z)
  //                 + Mc*128 (xdbl), plus alloc padding slack
  size_t persistent = off;
  int nc = 1;
  while (nc < 32){
    size_t need = (size_t)(M_ / nc) * 6272 + 8192;
    if (persistent + need <= ws_size) break;
    nc <<= 1;
  }
  const int Mc = M_ / nc;      // rows per chunk (multiple of L_)
  const int Bc = B_ / nc;      // batches per chunk
  u16* X   = (u16*)alloc((size_t)Mc * DI_ * 2);   // hosts hn (first Mc*DM_), then u
  u16* xu  = (u16*)alloc((size_t)Mc * DI_ * 2);   // u_pre, then delta, then gated y
  u16* xzs = (u16*)alloc((size_t)Mc * DI_ * 2);   // silu(z)
  u16* xdb = (u16*)alloc((size_t)Mc * 64 * 2);    // x_dbl
  u16* hn  = X;

  inproj_kernel<<<M_, 512, 0, stream>>>(x, ip_w, ip_b, h16);

  for (int i = 0; i < NL_; i++){
    for (int c = 0; c < nc; c++){
      u16* hc = h16 + (size_t)c * Mc * DM_;

      ln_kernel<<<Mc / 4, 256, 0, stream>>>(hc, ln_g + i * DM_, ln_b + i * DM_, hn);

      // fused: u_pre = hn @ w_in[0:DI]^T -> xu ; xzs = silu(hn @ w_in[DI:2DI]^T)
      gemm_bt<128, 128, 64, 4><<<dim3(2 * DI_ / 128, Mc / 128), 256, 0, stream>>>(
          hn, DM_, inpw + (size_t)i * 2 * DI_ * DM_, xu, xzs, nullptr, nullptr,
          2 * DI_, DM_, DI_);

      // u = silu(causal_conv(u_pre)); hn (in X) is dead now
      conv_kernel<<<(Mc * DI_) / 256, 256, 0, stream>>>(
          xu, convw + i * DI_ * DC_, convb + i * DI_, X);

      // x_dbl = u @ x_proj^T
      gemm_bt<128, 64, 64, 0><<<dim3(1, Mc / 128), 256, 0, stream>>>(
          X, DI_, xpw + (size_t)i * 64 * DI_, xdb, nullptr, nullptr, nullptr,
          64, DI_, 0);

      // delta = softplus(dt @ dt_w^T + dt_b) -> overwrites xu (u_pre dead)
      gemm_bt<128, 128, 32, 1><<<dim3(DI_ / 128, Mc / 128), 256, 0, stream>>>(
          xdb, 64, dtw + (size_t)i * DI_ * DTR_, xu, nullptr, dtb + i * DI_, nullptr,
          DI_, DTR_, 0);

      // scan + gate: xu <- (scan(y) + u*D) * silu(z), in place
      scan_kernel<<<dim3(DI_ / 256, Bc), 256, 0, stream>>>(
          xu, X, xdb, xzs, Alog + (size_t)i * DI_ * DS_, Dp + i * DI_);

      // h += y_gated @ out_w^T
      gemm_bt<128, 128, 64, 2><<<dim3(DM_ / 128, Mc / 128), 256, 0, stream>>>(
          xu, DI_, outw + (size_t)i * DM_ * DI_, hc, nullptr, nullptr, hc,
          DM_, DI_, 0);
    }
  }

  pool_kernel<<<dim3(2, B_, 8), 256, 0, stream>>>(h16, part);
  fc_kernel<<<B_, 256, 0, stream>>>(part, fcw, fcb, out);
}

// Round 4
// 3584.724 us; speedup vs baseline: 1.1300x; 1.1300x over previous
//
#include <hip/hip_runtime.h>
#include <hip/hip_bf16.h>

#define B_   32
#define L_   1024
#define DIN_ 9
#define DM_  512
#define NL_  4
#define DI_  1024
#define DS_  16
#define DC_  4
#define DTR_ 32
#define NC_  12
#define M_   (B_*L_)
#define NCH_ 16
#define CHT_ 64   // L_/NCH_

typedef unsigned short u16;
typedef __attribute__((ext_vector_type(8))) short bf16x8;
typedef __attribute__((ext_vector_type(4))) float f32x4;

__device__ __forceinline__ float bf2f(u16 h){
  union { unsigned int u; float f; } v; v.u = ((unsigned int)h) << 16; return v.f;
}
__device__ __forceinline__ u16 f2bf(float f){
  union { float f; unsigned int u; } v; v.f = f;
  unsigned int u = v.u;
  return (u16)((u + 0x7fffu + ((u >> 16) & 1u)) >> 16);
}

// ---------------- input projection: h = bf16(x @ ip_w^T + ip_b) ----------------
__global__ __launch_bounds__(512) void inproj_kernel(const float* __restrict__ x,
                                                     const float* __restrict__ w,
                                                     const float* __restrict__ bias,
                                                     u16* __restrict__ h){
  int m = blockIdx.x;          // 0..32767
  int d = threadIdx.x;         // 0..511
  __shared__ float xr[DIN_];
  if (threadIdx.x < DIN_) xr[threadIdx.x] = x[(size_t)m * DIN_ + threadIdx.x];
  __syncthreads();
  float a = bias[d];
#pragma unroll
  for (int i = 0; i < DIN_; i++) a += xr[i] * w[d * DIN_ + i];
  h[(size_t)m * DM_ + d] = f2bf(a);
}

// ---------------- layernorm: bf16 h -> bf16 hn ----------------
__global__ __launch_bounds__(256) void ln_kernel(const u16* __restrict__ h,
                                                 const float* __restrict__ g,
                                                 const float* __restrict__ bt,
                                                 u16* __restrict__ hn){
  int row = blockIdx.x * 4 + (threadIdx.x >> 6);
  int lane = threadIdx.x & 63;
  const u16* hr = h + (size_t)row * DM_ + lane * 8;
  ushort4 a0 = *(const ushort4*)(hr);
  ushort4 a1 = *(const ushort4*)(hr + 4);
  float v[8];
  v[0]=bf2f(a0.x); v[1]=bf2f(a0.y); v[2]=bf2f(a0.z); v[3]=bf2f(a0.w);
  v[4]=bf2f(a1.x); v[5]=bf2f(a1.y); v[6]=bf2f(a1.z); v[7]=bf2f(a1.w);
  float s = 0.f, q = 0.f;
#pragma unroll
  for (int i = 0; i < 8; i++){ s += v[i]; q += v[i]*v[i]; }
#pragma unroll
  for (int o = 32; o; o >>= 1){ s += __shfl_xor(s, o); q += __shfl_xor(q, o); }
  float mean = s * (1.f / DM_);
  float rstd = rsqrtf(q * (1.f / DM_) - mean * mean + 1e-5f);
  float4 g0 = *(const float4*)(g + lane * 8);
  float4 g1 = *(const float4*)(g + lane * 8 + 4);
  float4 b0 = *(const float4*)(bt + lane * 8);
  float4 b1 = *(const float4*)(bt + lane * 8 + 4);
  ushort4 o0, o1;
  o0.x = f2bf((v[0]-mean)*rstd*g0.x + b0.x);
  o0.y = f2bf((v[1]-mean)*rstd*g0.y + b0.y);
  o0.z = f2bf((v[2]-mean)*rstd*g0.z + b0.z);
  o0.w = f2bf((v[3]-mean)*rstd*g0.w + b0.w);
  o1.x = f2bf((v[4]-mean)*rstd*g1.x + b1.x);
  o1.y = f2bf((v[5]-mean)*rstd*g1.y + b1.y);
  o1.z = f2bf((v[6]-mean)*rstd*g1.z + b1.z);
  o1.w = f2bf((v[7]-mean)*rstd*g1.w + b1.w);
  u16* op = hn + (size_t)row * DM_ + lane * 8;
  *(ushort4*)(op)     = o0;
  *(ushort4*)(op + 4) = o1;
}

// ---------------- GEMM: C[M][N] = A[M][K] (bf16) @ W[N][K]^T (fp32->bf16 on the fly) --
// EPI 0: store bf16. EPI 1: bf16(softplus(v + bias[n])). EPI 2: bf16(v + Res) residual
// (Cb may alias Res). EPI 4: split output: n<nsplit -> Cb (raw), else Cb2 (silu), both
// with row stride nsplit.
template<int BM, int BN, int BK, int EPI>
__global__ __launch_bounds__(256)
void gemm_bt(const u16* __restrict__ A, int lda,
             const float* __restrict__ Bw,
             u16* Cb, u16* Cb2, const float* __restrict__ bias,
             const u16* Res, int N, int K, int nsplit){
  constexpr int CH = BK / 8;
  constexpr int MASK = CH - 1;
  constexpr int WM = BM / 2, WN = BN / 2;
  constexpr int FM = WM / 16, FN = WN / 16;
  __shared__ u16 As[BM * BK];
  __shared__ u16 Bs[BN * BK];
  const int tid = threadIdx.x;
  const int lane = tid & 63;
  const int wid = tid >> 6;
  const int wr = wid >> 1, wc = wid & 1;
  const int bm = blockIdx.y * BM, bn = blockIdx.x * BN;
  f32x4 acc[FM][FN];
#pragma unroll
  for (int i = 0; i < FM; i++)
#pragma unroll
    for (int j = 0; j < FN; j++) acc[i][j] = f32x4{0.f, 0.f, 0.f, 0.f};
  constexpr int LA = BM * BK / (256 * 8);
  constexpr int LB = BN * BK / (256 * 8);
  for (int k0 = 0; k0 < K; k0 += BK){
    __syncthreads();
#pragma unroll
    for (int i = 0; i < LA; i++){
      int chunk = i * 256 + tid;
      int row = chunk / CH, cc = chunk & MASK;
      uint4 v = *(const uint4*)(A + (size_t)(bm + row) * lda + k0 + cc * 8);
      *(uint4*)(&As[row * BK + ((cc ^ (row & MASK))) * 8]) = v;
    }
#pragma unroll
    for (int i = 0; i < LB; i++){
      int chunk = i * 256 + tid;
      int row = chunk / CH, cc = chunk & MASK;
      const float* bp = Bw + (size_t)(bn + row) * K + k0 + cc * 8;
      float4 f0 = *(const float4*)(bp);
      float4 f1 = *(const float4*)(bp + 4);
      ushort4 h0, h1;
      h0.x = f2bf(f0.x); h0.y = f2bf(f0.y); h0.z = f2bf(f0.z); h0.w = f2bf(f0.w);
      h1.x = f2bf(f1.x); h1.y = f2bf(f1.y); h1.z = f2bf(f1.z); h1.w = f2bf(f1.w);
      u16* dst = &Bs[row * BK + ((cc ^ (row & MASK))) * 8];
      *(ushort4*)(dst)     = h0;
      *(ushort4*)(dst + 4) = h1;
    }
    __syncthreads();
#pragma unroll
    for (int kk = 0; kk < BK / 32; kk++){
      bf16x8 af[FM], bfr[FN];
      const int kch = kk * 4 + (lane >> 4);
#pragma unroll
      for (int mi = 0; mi < FM; mi++){
        int r = wr * WM + mi * 16 + (lane & 15);
        af[mi] = *(const bf16x8*)(&As[r * BK + ((kch ^ (r & MASK))) * 8]);
      }
#pragma unroll
      for (int ni = 0; ni < FN; ni++){
        int r = wc * WN + ni * 16 + (lane & 15);
        bfr[ni] = *(const bf16x8*)(&Bs[r * BK + ((kch ^ (r & MASK))) * 8]);
      }
#pragma unroll
      for (int mi = 0; mi < FM; mi++)
#pragma unroll
        for (int ni = 0; ni < FN; ni++)
          acc[mi][ni] = __builtin_amdgcn_mfma_f32_16x16x32_bf16(af[mi], bfr[ni], acc[mi][ni], 0, 0, 0);
    }
  }
  const int rq = (lane >> 4) * 4, cl = lane & 15;
#pragma unroll
  for (int mi = 0; mi < FM; mi++){
#pragma unroll
    for (int ni = 0; ni < FN; ni++){
      const int n = bn + wc * WN + ni * 16 + cl;
#pragma unroll
      for (int j = 0; j < 4; j++){
        const int m = bm + wr * WM + mi * 16 + rq + j;
        float v = acc[mi][ni][j];
        if constexpr (EPI == 0){
          Cb[(size_t)m * N + n] = f2bf(v);
        } else if constexpr (EPI == 1){
          float xx = v + bias[n];
          float sp = (xx > 20.f) ? xx : log1pf(__expf(xx));
          Cb[(size_t)m * N + n] = f2bf(sp);
        } else if constexpr (EPI == 2){
          const size_t off = (size_t)m * N + n;
          Cb[off] = f2bf(v + bf2f(Res[off]));
        } else {
          if (n < nsplit){
            Cb[(size_t)m * nsplit + n] = f2bf(v);
          } else {
            float sg = v / (1.f + __expf(-v));
            Cb2[(size_t)m * nsplit + (n - nsplit)] = f2bf(sg);
          }
        }
      }
    }
  }
}

// ---------------- causal depthwise conv (DC=4) + SiLU ----------------
__global__ __launch_bounds__(256) void conv_kernel(const u16* __restrict__ xu,
                                                   const float* __restrict__ cw,
                                                   const float* __restrict__ cb,
                                                   u16* __restrict__ u){
  int idx = blockIdx.x * 256 + threadIdx.x;        // over Mc*DI
  int e = idx & (DI_ - 1);
  int bl = idx >> 10;
  int l = bl & (L_ - 1);
  const u16* p = xu + (size_t)bl * DI_ + e;
  float w0 = cw[e * 4 + 0], w1 = cw[e * 4 + 1], w2 = cw[e * 4 + 2], w3 = cw[e * 4 + 3];
  float a = cb[e];
  a += bf2f(p[0]) * w3;
  if (l >= 1) a += bf2f(*(p - DI_)) * w2;
  if (l >= 2) a += bf2f(*(p - 2 * DI_)) * w1;
  if (l >= 3) a += bf2f(*(p - 3 * DI_)) * w0;
  float sg = a / (1.f + __expf(-a));
  u[idx] = f2bf(sg);
}

// ---------------- scan pass 1: per-chunk (a_prod, h_part), h0 = 0 ----------------
// grid (DI/256, NCH, Bc); sb layout [c][b*DI+e][32]: [0..15]=a_prod, [16..31]=h_part
__global__ __launch_bounds__(256)
void scan1_kernel(const u16* __restrict__ dlt, const u16* __restrict__ u,
                  const u16* __restrict__ xdbl,
                  const float* __restrict__ A_log,
                  float* __restrict__ sb, int BE){
  const int tid = threadIdx.x;
  const int e = blockIdx.x * 256 + tid;
  const int c = blockIdx.y;
  const int b = blockIdx.z;
  __shared__ float Bsh[CHT_][DS_];     // 4 KB
  if (tid < 128){
    int row = tid >> 1, col = (tid & 1) * 8;
    const u16* p = xdbl + ((size_t)b * L_ + (size_t)c * CHT_ + row) * 64 + 32 + col;
    ushort4 v0 = *(const ushort4*)p;
    ushort4 v1 = *(const ushort4*)(p + 4);
    Bsh[row][col+0] = bf2f(v0.x); Bsh[row][col+1] = bf2f(v0.y);
    Bsh[row][col+2] = bf2f(v0.z); Bsh[row][col+3] = bf2f(v0.w);
    Bsh[row][col+4] = bf2f(v1.x); Bsh[row][col+5] = bf2f(v1.y);
    Bsh[row][col+6] = bf2f(v1.z); Bsh[row][col+7] = bf2f(v1.w);
  }
  __syncthreads();
  float As[DS_];
#pragma unroll
  for (int s = 0; s < DS_; s++) As[s] = -__expf(A_log[e * DS_ + s]);
  float h[DS_];
#pragma unroll
  for (int s = 0; s < DS_; s++) h[s] = 0.f;
  float sdd = 0.f;
  const size_t base = ((size_t)b * L_ + (size_t)c * CHT_) * DI_ + e;
  for (int t = 0; t < CHT_; t++){
    float dd = bf2f(dlt[base + (size_t)t * DI_]);
    float uu = bf2f(u[base + (size_t)t * DI_]);
    sdd += dd;
    float du_ = dd * uu;
    const float* row = &Bsh[t][0];
    float4 B0 = *(const float4*)(row);
    float4 B1 = *(const float4*)(row + 4);
    float4 B2 = *(const float4*)(row + 8);
    float4 B3 = *(const float4*)(row + 12);
    float Bv[16] = {B0.x,B0.y,B0.z,B0.w, B1.x,B1.y,B1.z,B1.w,
                    B2.x,B2.y,B2.z,B2.w, B3.x,B3.y,B3.z,B3.w};
#pragma unroll
    for (int s = 0; s < DS_; s++)
      h[s] = __expf(dd * As[s]) * h[s] + du_ * Bv[s];
  }
  float* p = sb + ((size_t)c * BE + (size_t)b * DI_ + e) * 32;
#pragma unroll
  for (int s = 0; s < DS_; s++) p[s] = __expf(As[s] * sdd);
#pragma unroll
  for (int s = 0; s < DS_; s++) p[16 + s] = h[s];
}

// ---------------- scan pass 2: combine chunk summaries -> h_init per chunk --------
// one thread per (b,e); overwrites h_part slot with h_init (state BEFORE chunk c)
__global__ __launch_bounds__(256)
void scan2_kernel(float* __restrict__ sb, int BE){
  const int be = blockIdx.x * 256 + threadIdx.x;
  float h[DS_];
#pragma unroll
  for (int s = 0; s < DS_; s++) h[s] = 0.f;
  for (int c = 0; c < NCH_; c++){
    float* p = sb + ((size_t)c * BE + be) * 32;
    float4 a0 = *(const float4*)(p);
    float4 a1 = *(const float4*)(p + 4);
    float4 a2 = *(const float4*)(p + 8);
    float4 a3 = *(const float4*)(p + 12);
    float4 h0 = *(const float4*)(p + 16);
    float4 h1 = *(const float4*)(p + 20);
    float4 h2 = *(const float4*)(p + 24);
    float4 h3 = *(const float4*)(p + 28);
    float av[16] = {a0.x,a0.y,a0.z,a0.w, a1.x,a1.y,a1.z,a1.w,
                    a2.x,a2.y,a2.z,a2.w, a3.x,a3.y,a3.z,a3.w};
    float hv[16] = {h0.x,h0.y,h0.z,h0.w, h1.x,h1.y,h1.z,h1.w,
                    h2.x,h2.y,h2.z,h2.w, h3.x,h3.y,h3.z,h3.w};
    float4 w0, w1, w2, w3;
    float* wv[4] = {&w0.x, &w1.x, &w2.x, &w3.x};
#pragma unroll
    for (int s = 0; s < DS_; s++){
      float hi = h[s];
      h[s] = av[s] * hi + hv[s];
      wv[s >> 2][s & 3] = hi;
    }
    *(float4*)(p + 16) = w0;
    *(float4*)(p + 20) = w1;
    *(float4*)(p + 24) = w2;
    *(float4*)(p + 28) = w3;
  }
}

// ---------------- scan pass 3: rescan with h_init, emit gated y (in place) --------
__global__ __launch_bounds__(256)
void scan3_kernel(u16* __restrict__ dy,       // in: delta; out: gated y
                  const u16* __restrict__ u, const u16* __restrict__ xdbl,
                  const u16* __restrict__ zs,
                  const float* __restrict__ A_log, const float* __restrict__ Dp,
                  const float* __restrict__ sb, int BE){
  const int tid = threadIdx.x;
  const int e = blockIdx.x * 256 + tid;
  const int c = blockIdx.y;
  const int b = blockIdx.z;
  __shared__ float BC[CHT_][32];       // 8 KB
  {
    int row = tid >> 2, col = (tid & 3) * 8;
    const u16* p = xdbl + ((size_t)b * L_ + (size_t)c * CHT_ + row) * 64 + 32 + col;
    ushort4 v0 = *(const ushort4*)p;
    ushort4 v1 = *(const ushort4*)(p + 4);
    BC[row][col+0] = bf2f(v0.x); BC[row][col+1] = bf2f(v0.y);
    BC[row][col+2] = bf2f(v0.z); BC[row][col+3] = bf2f(v0.w);
    BC[row][col+4] = bf2f(v1.x); BC[row][col+5] = bf2f(v1.y);
    BC[row][col+6] = bf2f(v1.z); BC[row][col+7] = bf2f(v1.w);
  }
  __syncthreads();
  float As[DS_];
#pragma unroll
  for (int s = 0; s < DS_; s++) As[s] = -__expf(A_log[e * DS_ + s]);
  const float Dv = Dp[e];
  const float* ip = sb + ((size_t)c * BE + (size_t)b * DI_ + e) * 32 + 16;
  float h[DS_];
#pragma unroll
  for (int s = 0; s < DS_; s++) h[s] = ip[s];
  const size_t base = ((size_t)b * L_ + (size_t)c * CHT_) * DI_ + e;
  for (int t = 0; t < CHT_; t++){
    const size_t idx = base + (size_t)t * DI_;
    float dd = bf2f(dy[idx]);
    float uu = bf2f(u[idx]);
    float du_ = dd * uu;
    const float* row = &BC[t][0];
    float4 B0 = *(const float4*)(row);
    float4 B1 = *(const float4*)(row + 4);
    float4 B2 = *(const float4*)(row + 8);
    float4 B3 = *(const float4*)(row + 12);
    float4 C0 = *(const float4*)(row + 16);
    float4 C1 = *(const float4*)(row + 20);
    float4 C2 = *(const float4*)(row + 24);
    float4 C3 = *(const float4*)(row + 28);
    float Bv[16] = {B0.x,B0.y,B0.z,B0.w, B1.x,B1.y,B1.z,B1.w,
                    B2.x,B2.y,B2.z,B2.w, B3.x,B3.y,B3.z,B3.w};
    float Cv[16] = {C0.x,C0.y,C0.z,C0.w, C1.x,C1.y,C1.z,C1.w,
                    C2.x,C2.y,C2.z,C2.w, C3.x,C3.y,C3.z,C3.w};
    float yv = 0.f;
#pragma unroll
    for (int s = 0; s < DS_; s++){
      h[s] = __expf(dd * As[s]) * h[s] + du_ * Bv[s];
      yv += h[s] * Cv[s];
    }
    float zv = bf2f(zs[idx]);
    dy[idx] = f2bf((yv + uu * Dv) * zv);
  }
}

// ---------------- mean-pool partials over L (bf16 h) ----------------
__global__ __launch_bounds__(256) void pool_kernel(const u16* __restrict__ h,
                                                   float* __restrict__ part){
  int d = blockIdx.x * 256 + threadIdx.x;  // 0..511 (2 blocks)
  int b = blockIdx.y;
  int p = blockIdx.z;                      // 8 chunks of 128
  float s = 0.f;
  const u16* hp = h + ((size_t)b * L_ + p * 128) * DM_ + d;
  for (int l = 0; l < 128; l++) s += bf2f(hp[(size_t)l * DM_]);
  part[((size_t)p * B_ + b) * DM_ + d] = s;
}

// ---------------- final FC ----------------
__global__ __launch_bounds__(256) void fc_kernel(const float* __restrict__ part,
                                                 const float* __restrict__ fcw,
                                                 const float* __restrict__ fcb,
                                                 float* __restrict__ out){
  int b = blockIdx.x;
  int tid = threadIdx.x;
  __shared__ float pd[DM_];
  for (int d = tid; d < DM_; d += 256){
    float s = 0.f;
    for (int p = 0; p < 8; p++) s += part[((size_t)p * B_ + b) * DM_ + d];
    pd[d] = s * (1.f / L_);
  }
  __syncthreads();
  int wid = tid >> 6, lane = tid & 63;
  for (int c = wid; c < NC_; c += 4){
    float s = 0.f;
    for (int d = lane; d < DM_; d += 64) s += pd[d] * fcw[c * DM_ + d];
#pragma unroll
    for (int o = 32; o; o >>= 1) s += __shfl_xor(s, o);
    if (lane == 0) out[b * NC_ + c] = s + fcb[c];
  }
}

extern "C" void kernel_launch(void* const* d_in, const int* in_sizes, int n_in,
                              void* d_out, int out_size, void* d_ws, size_t ws_size,
                              hipStream_t stream){
  const float* x     = (const float*)d_in[0];
  const float* ip_w  = (const float*)d_in[1];
  const float* ip_b  = (const float*)d_in[2];
  const float* ln_g  = (const float*)d_in[3];
  const float* ln_b  = (const float*)d_in[4];
  const float* inpw  = (const float*)d_in[5];
  const float* convw = (const float*)d_in[6];
  const float* convb = (const float*)d_in[7];
  const float* xpw   = (const float*)d_in[8];
  const float* dtw   = (const float*)d_in[9];
  const float* dtb   = (const float*)d_in[10];
  const float* Alog  = (const float*)d_in[11];
  const float* Dp    = (const float*)d_in[12];
  const float* outw  = (const float*)d_in[13];
  const float* fcw   = (const float*)d_in[14];
  const float* fcb   = (const float*)d_in[15];
  float* out = (float*)d_out;

  char* ws = (char*)d_ws;
  size_t off = 0;
  auto alloc = [&](size_t bytes) -> void* {
    void* p = ws + off; off += (bytes + 255) & ~(size_t)255; return p;
  };
  // ---- persistent (~32.5 MB): residual h (bf16) + pool partials ----
  u16*   h16  = (u16*)  alloc((size_t)M_ * DM_ * 2);            // 32 MB
  float* part = (float*)alloc((size_t)8 * B_ * DM_ * 4);        // 0.5 MB

  // ---- choose batch-chunking so per-chunk buffers fit ws_size ----
  // per-chunk bytes = Mc*2048 (X) + Mc*2048 (xu) + Mc*2048 (xzs) + Mc*128 (xdbl)
  //                 + Mc*2048 (scan summaries fp32), plus alloc padding slack
  size_t persistent = off;
  int nc = 1;
  while (nc < 32){
    size_t need = (size_t)(M_ / nc) * 8320 + 16384;
    if (persistent + need <= ws_size) break;
    nc <<= 1;
  }
  const int Mc = M_ / nc;      // rows per chunk (multiple of L_)
  const int Bc = B_ / nc;      // batches per chunk
  const int BE = Bc * DI_;
  u16* X   = (u16*)alloc((size_t)Mc * DI_ * 2);   // hosts hn (first Mc*DM_), then u
  u16* xu  = (u16*)alloc((size_t)Mc * DI_ * 2);   // u_pre, then delta, then gated y
  u16* xzs = (u16*)alloc((size_t)Mc * DI_ * 2);   // silu(z)
  u16* xdb = (u16*)alloc((size_t)Mc * 64 * 2);    // x_dbl
  float* sb = (float*)alloc((size_t)Mc * 2048);   // scan summaries [NCH][BE][32] f32
  u16* hn  = X;

  inproj_kernel<<<M_, 512, 0, stream>>>(x, ip_w, ip_b, h16);

  for (int i = 0; i < NL_; i++){
    for (int c = 0; c < nc; c++){
      u16* hc = h16 + (size_t)c * Mc * DM_;

      ln_kernel<<<Mc / 4, 256, 0, stream>>>(hc, ln_g + i * DM_, ln_b + i * DM_, hn);

      // fused: u_pre = hn @ w_in[0:DI]^T -> xu ; xzs = silu(hn @ w_in[DI:2DI]^T)
      gemm_bt<128, 128, 64, 4><<<dim3(2 * DI_ / 128, Mc / 128), 256, 0, stream>>>(
          hn, DM_, inpw + (size_t)i * 2 * DI_ * DM_, xu, xzs, nullptr, nullptr,
          2 * DI_, DM_, DI_);

      // u = silu(causal_conv(u_pre)); hn (in X) is dead now
      conv_kernel<<<(Mc * DI_) / 256, 256, 0, stream>>>(
          xu, convw + i * DI_ * DC_, convb + i * DI_, X);

      // x_dbl = u @ x_proj^T
      gemm_bt<128, 64, 64, 0><<<dim3(1, Mc / 128), 256, 0, stream>>>(
          X, DI_, xpw + (size_t)i * 64 * DI_, xdb, nullptr, nullptr, nullptr,
          64, DI_, 0);

      // delta = softplus(dt @ dt_w^T + dt_b) -> overwrites xu (u_pre dead)
      gemm_bt<128, 128, 32, 1><<<dim3(DI_ / 128, Mc / 128), 256, 0, stream>>>(
          xdb, 64, dtw + (size_t)i * DI_ * DTR_, xu, nullptr, dtb + i * DI_, nullptr,
          DI_, DTR_, 0);

      // chunk-parallel scan: pass1 summaries, pass2 combine, pass3 rescan + gate
      scan1_kernel<<<dim3(DI_ / 256, NCH_, Bc), 256, 0, stream>>>(
          xu, X, xdb, Alog + (size_t)i * DI_ * DS_, sb, BE);
      scan2_kernel<<<BE / 256, 256, 0, stream>>>(sb, BE);
      scan3_kernel<<<dim3(DI_ / 256, NCH_, Bc), 256, 0, stream>>>(
          xu, X, xdb, xzs, Alog + (size_t)i * DI_ * DS_, Dp + i * DI_, sb, BE);

      // h += y_gated @ out_w^T
      gemm_bt<128, 128, 64, 2><<<dim3(DM_ / 128, Mc / 128), 256, 0, stream>>>(
          xu, DI_, outw + (size_t)i * DM_ * DI_, hc, nullptr, nullptr, hc,
          DM_, DI_, 0);
    }
  }

  pool_kernel<<<dim3(2, B_, 8), 256, 0, stream>>>(h16, part);
  fc_kernel<<<B_, 256, 0, stream>>>(part, fcw, fcb, out);
}

// Round 5
// 3491.630 us; speedup vs baseline: 1.1601x; 1.0267x over previous
//
#include <hip/hip_runtime.h>
#include <hip/hip_bf16.h>

#define B_   32
#define L_   1024
#define DIN_ 9
#define DM_  512
#define NL_  4
#define DI_  1024
#define DS_  16
#define DC_  4
#define DTR_ 32
#define NC_  12
#define M_   (B_*L_)
#define NCH_ 8
#define CHT_ 128   // L_/NCH_

typedef unsigned short u16;
typedef __attribute__((ext_vector_type(8))) short bf16x8;
typedef __attribute__((ext_vector_type(4))) float f32x4;

__device__ __forceinline__ float bf2f(u16 h){
  union { unsigned int u; float f; } v; v.u = ((unsigned int)h) << 16; return v.f;
}
__device__ __forceinline__ u16 f2bf(float f){
  union { float f; unsigned int u; } v; v.f = f;
  unsigned int u = v.u;
  return (u16)((u + 0x7fffu + ((u >> 16) & 1u)) >> 16);
}
__device__ __forceinline__ float siluf(float x){ return x / (1.f + __expf(-x)); }

// ---------------- one-shot weight cast fp32 -> bf16 (3 arrays, 1 dispatch) --------
#define NW1_ (NL_*2*DI_*DM_)
#define NW2_ (NL_*64*DI_)
#define NW3_ (NL_*DM_*DI_)
__global__ __launch_bounds__(256) void cast3_kernel(const float* __restrict__ a,
                                                    const float* __restrict__ b,
                                                    const float* __restrict__ c,
                                                    u16* __restrict__ oa,
                                                    u16* __restrict__ ob,
                                                    u16* __restrict__ oc){
  int i = blockIdx.x * 256 + threadIdx.x;
  if (i < NW1_) oa[i] = f2bf(a[i]);
  else if (i < NW1_ + NW2_) ob[i - NW1_] = f2bf(b[i - NW1_]);
  else if (i < NW1_ + NW2_ + NW3_) oc[i - NW1_ - NW2_] = f2bf(c[i - NW1_ - NW2_]);
}

// ---------------- input projection: h = bf16(x @ ip_w^T + ip_b) ----------------
__global__ __launch_bounds__(512) void inproj_kernel(const float* __restrict__ x,
                                                     const float* __restrict__ w,
                                                     const float* __restrict__ bias,
                                                     u16* __restrict__ h){
  int m = blockIdx.x;
  int d = threadIdx.x;
  __shared__ float xr[DIN_];
  if (threadIdx.x < DIN_) xr[threadIdx.x] = x[(size_t)m * DIN_ + threadIdx.x];
  __syncthreads();
  float a = bias[d];
#pragma unroll
  for (int i = 0; i < DIN_; i++) a += xr[i] * w[d * DIN_ + i];
  h[(size_t)m * DM_ + d] = f2bf(a);
}

// ---------------- LN row stats: (mean, rstd) per row ----------------
__global__ __launch_bounds__(256) void lnstats_kernel(const u16* __restrict__ h,
                                                      float2* __restrict__ st){
  int row = blockIdx.x * 4 + (threadIdx.x >> 6);
  int lane = threadIdx.x & 63;
  const u16* hr = h + (size_t)row * DM_ + lane * 8;
  ushort4 a0 = *(const ushort4*)(hr);
  ushort4 a1 = *(const ushort4*)(hr + 4);
  float v[8];
  v[0]=bf2f(a0.x); v[1]=bf2f(a0.y); v[2]=bf2f(a0.z); v[3]=bf2f(a0.w);
  v[4]=bf2f(a1.x); v[5]=bf2f(a1.y); v[6]=bf2f(a1.z); v[7]=bf2f(a1.w);
  float s = 0.f, q = 0.f;
#pragma unroll
  for (int i = 0; i < 8; i++){ s += v[i]; q += v[i]*v[i]; }
#pragma unroll
  for (int o = 32; o; o >>= 1){ s += __shfl_xor(s, o); q += __shfl_xor(q, o); }
  if (lane == 0){
    float mean = s * (1.f / DM_);
    float rstd = rsqrtf(q * (1.f / DM_) - mean * mean + 1e-5f);
    st[row] = make_float2(mean, rstd);
  }
}

// ---------------- GEMM: C[M][N] = stage(A)[M][K] @ W[N][K]^T (both bf16 MFMA) ------
// STAGE 0: A is bf16, plain copy.
// STAGE 1: A is bf16 h; apply LN with stats[m], gamma/beta[k] during staging.
// STAGE 2: A is bf16 u_pre; apply causal depthwise conv (DC=4) + SiLU during staging.
// EPI 0: store bf16. EPI 2: bf16(v + Res) residual (Cb may alias Res).
// EPI 4: split: n<nsplit -> Cb raw; else Cb2 = silu(v); both row stride nsplit.
template<int BM, int BN, int BK, int EPI, int STAGE>
__global__ __launch_bounds__(256)
void gemm_bt(const u16* __restrict__ A, int lda,
             const u16* __restrict__ Bw,
             u16* Cb, u16* Cb2, const u16* Res,
             const float2* __restrict__ stats,
             const float* __restrict__ gmm, const float* __restrict__ bta,
             const float* __restrict__ cwp, const float* __restrict__ cbp,
             int N, int K, int nsplit){
  constexpr int CH = BK / 8;
  constexpr int MASK = CH - 1;
  constexpr int WM = BM / 2, WN = BN / 2;
  constexpr int FM = WM / 16, FN = WN / 16;
  __shared__ u16 As_[BM * BK];
  __shared__ u16 Bs_[BN * BK];
  const int tid = threadIdx.x;
  const int lane = tid & 63;
  const int wid = tid >> 6;
  const int wr = wid >> 1, wc = wid & 1;
  const int bm = blockIdx.y * BM, bn = blockIdx.x * BN;
  const int cc0 = tid & MASK;          // fixed column-chunk of this thread (256%CH==0)
  f32x4 acc[FM][FN];
#pragma unroll
  for (int i = 0; i < FM; i++)
#pragma unroll
    for (int j = 0; j < FN; j++) acc[i][j] = f32x4{0.f, 0.f, 0.f, 0.f};
  constexpr int LA = BM * BK / (256 * 8);
  constexpr int LB = BN * BK / (256 * 8);
  for (int k0 = 0; k0 < K; k0 += BK){
    // per-k0 column-constant staging params
    float gv[8], bv[8];
    float cwv[4][8], cbv[8];
    if constexpr (STAGE == 1){
      const int col0 = k0 + cc0 * 8;
      float4 g0 = *(const float4*)(gmm + col0);
      float4 g1 = *(const float4*)(gmm + col0 + 4);
      float4 b0 = *(const float4*)(bta + col0);
      float4 b1 = *(const float4*)(bta + col0 + 4);
      gv[0]=g0.x; gv[1]=g0.y; gv[2]=g0.z; gv[3]=g0.w;
      gv[4]=g1.x; gv[5]=g1.y; gv[6]=g1.z; gv[7]=g1.w;
      bv[0]=b0.x; bv[1]=b0.y; bv[2]=b0.z; bv[3]=b0.w;
      bv[4]=b1.x; bv[5]=b1.y; bv[6]=b1.z; bv[7]=b1.w;
    } else if constexpr (STAGE == 2){
      const int col0 = k0 + cc0 * 8;
#pragma unroll
      for (int j = 0; j < 8; j++){
        float4 w4 = *(const float4*)(cwp + (size_t)(col0 + j) * 4);
        cwv[0][j]=w4.x; cwv[1][j]=w4.y; cwv[2][j]=w4.z; cwv[3][j]=w4.w;
      }
      float4 c0 = *(const float4*)(cbp + col0);
      float4 c1 = *(const float4*)(cbp + col0 + 4);
      cbv[0]=c0.x; cbv[1]=c0.y; cbv[2]=c0.z; cbv[3]=c0.w;
      cbv[4]=c1.x; cbv[5]=c1.y; cbv[6]=c1.z; cbv[7]=c1.w;
    }
    __syncthreads();
#pragma unroll
    for (int i = 0; i < LA; i++){
      int chunk = i * 256 + tid;
      int row = chunk / CH, cc = chunk & MASK;
      u16* dst = &As_[row * BK + ((cc ^ (row & MASK))) * 8];
      if constexpr (STAGE == 0){
        uint4 v = *(const uint4*)(A + (size_t)(bm + row) * lda + k0 + cc * 8);
        *(uint4*)dst = v;
      } else if constexpr (STAGE == 1){
        const int m = bm + row;
        float2 stt = stats[m];
        const u16* p = A + (size_t)m * lda + k0 + cc * 8;
        ushort4 q0 = *(const ushort4*)p, q1 = *(const ushort4*)(p + 4);
        ushort4 h0, h1;
        h0.x = f2bf((bf2f(q0.x)-stt.x)*stt.y*gv[0]+bv[0]);
        h0.y = f2bf((bf2f(q0.y)-stt.x)*stt.y*gv[1]+bv[1]);
        h0.z = f2bf((bf2f(q0.z)-stt.x)*stt.y*gv[2]+bv[2]);
        h0.w = f2bf((bf2f(q0.w)-stt.x)*stt.y*gv[3]+bv[3]);
        h1.x = f2bf((bf2f(q1.x)-stt.x)*stt.y*gv[4]+bv[4]);
        h1.y = f2bf((bf2f(q1.y)-stt.x)*stt.y*gv[5]+bv[5]);
        h1.z = f2bf((bf2f(q1.z)-stt.x)*stt.y*gv[6]+bv[6]);
        h1.w = f2bf((bf2f(q1.w)-stt.x)*stt.y*gv[7]+bv[7]);
        *(ushort4*)dst = h0;
        *(ushort4*)(dst + 4) = h1;
      } else {
        const int m = bm + row;
        const int l = m & (L_ - 1);
        const u16* pb = A + (size_t)m * lda + k0 + cc * 8;
        float acc8[8];
#pragma unroll
        for (int j = 0; j < 8; j++) acc8[j] = cbv[j];
#pragma unroll
        for (int d = 0; d < 4; d++){
          const bool ok = (l - 3 + d) >= 0;
          const u16* p = ok ? (pb - (size_t)(3 - d) * lda) : pb;
          ushort4 q0 = *(const ushort4*)p, q1 = *(const ushort4*)(p + 4);
          float uv[8] = {bf2f(q0.x), bf2f(q0.y), bf2f(q0.z), bf2f(q0.w),
                         bf2f(q1.x), bf2f(q1.y), bf2f(q1.z), bf2f(q1.w)};
#pragma unroll
          for (int j = 0; j < 8; j++) acc8[j] += (ok ? uv[j] : 0.f) * cwv[d][j];
        }
        ushort4 h0, h1;
        h0.x = f2bf(siluf(acc8[0])); h0.y = f2bf(siluf(acc8[1]));
        h0.z = f2bf(siluf(acc8[2])); h0.w = f2bf(siluf(acc8[3]));
        h1.x = f2bf(siluf(acc8[4])); h1.y = f2bf(siluf(acc8[5]));
        h1.z = f2bf(siluf(acc8[6])); h1.w = f2bf(siluf(acc8[7]));
        *(ushort4*)dst = h0;
        *(ushort4*)(dst + 4) = h1;
      }
    }
#pragma unroll
    for (int i = 0; i < LB; i++){
      int chunk = i * 256 + tid;
      int row = chunk / CH, cc = chunk & MASK;
      uint4 v = *(const uint4*)(Bw + (size_t)(bn + row) * K + k0 + cc * 8);
      *(uint4*)(&Bs_[row * BK + ((cc ^ (row & MASK))) * 8]) = v;
    }
    __syncthreads();
#pragma unroll
    for (int kk = 0; kk < BK / 32; kk++){
      bf16x8 af[FM], bfr[FN];
      const int kch = kk * 4 + (lane >> 4);
#pragma unroll
      for (int mi = 0; mi < FM; mi++){
        int r = wr * WM + mi * 16 + (lane & 15);
        af[mi] = *(const bf16x8*)(&As_[r * BK + ((kch ^ (r & MASK))) * 8]);
      }
#pragma unroll
      for (int ni = 0; ni < FN; ni++){
        int r = wc * WN + ni * 16 + (lane & 15);
        bfr[ni] = *(const bf16x8*)(&Bs_[r * BK + ((kch ^ (r & MASK))) * 8]);
      }
#pragma unroll
      for (int mi = 0; mi < FM; mi++)
#pragma unroll
        for (int ni = 0; ni < FN; ni++)
          acc[mi][ni] = __builtin_amdgcn_mfma_f32_16x16x32_bf16(af[mi], bfr[ni], acc[mi][ni], 0, 0, 0);
    }
  }
  const int rq = (lane >> 4) * 4, cl = lane & 15;
#pragma unroll
  for (int mi = 0; mi < FM; mi++){
#pragma unroll
    for (int ni = 0; ni < FN; ni++){
      const int n = bn + wc * WN + ni * 16 + cl;
#pragma unroll
      for (int j = 0; j < 4; j++){
        const int m = bm + wr * WM + mi * 16 + rq + j;
        float v = acc[mi][ni][j];
        if constexpr (EPI == 0){
          Cb[(size_t)m * N + n] = f2bf(v);
        } else if constexpr (EPI == 2){
          const size_t off = (size_t)m * N + n;
          Cb[off] = f2bf(v + bf2f(Res[off]));
        } else {
          if (n < nsplit){
            Cb[(size_t)m * nsplit + n] = f2bf(v);
          } else {
            Cb2[(size_t)m * nsplit + (n - nsplit)] = f2bf(siluf(v));
          }
        }
      }
    }
  }
}

// ---------------- scan pass 1: fused conv+dt; per-chunk (a_prod, h_part) ----------
// grid (DI/256, NCH, B); sb layout [c][b*DI+e][32]: [0..15]=a_prod, [16..31]=h_part
__global__ __launch_bounds__(256)
void scan1_kernel(const u16* __restrict__ xu, const u16* __restrict__ xdb,
                  const float* __restrict__ dtw, const float* __restrict__ dtb,
                  const float* __restrict__ cwp, const float* __restrict__ cbp,
                  const float* __restrict__ A_log, float* __restrict__ sb){
  const int tid = threadIdx.x;
  const int e = blockIdx.x * 256 + tid;
  const int c = blockIdx.y, b = blockIdx.z;
  __shared__ float DT[CHT_][48];                 // 24 KB: cols 0..31 dt, 32..47 B
  {
    int row = tid >> 1, half = (tid & 1) * 24;
    const u16* p = xdb + ((size_t)b * L_ + (size_t)c * CHT_ + row) * 64 + half;
#pragma unroll
    for (int q = 0; q < 6; q++){
      ushort4 v = *(const ushort4*)(p + q * 4);
      DT[row][half + q*4 + 0] = bf2f(v.x);
      DT[row][half + q*4 + 1] = bf2f(v.y);
      DT[row][half + q*4 + 2] = bf2f(v.z);
      DT[row][half + q*4 + 3] = bf2f(v.w);
    }
  }
  __syncthreads();
  float As[DS_];
#pragma unroll
  for (int s = 0; s < DS_; s++) As[s] = -__expf(A_log[e * DS_ + s]);
  float dw[32];
#pragma unroll
  for (int q = 0; q < 8; q++){
    float4 w4 = *(const float4*)(dtw + (size_t)e * DTR_ + q * 4);
    dw[q*4]=w4.x; dw[q*4+1]=w4.y; dw[q*4+2]=w4.z; dw[q*4+3]=w4.w;
  }
  const float dtbe = dtb[e];
  const float4 cwv = *(const float4*)(cwp + (size_t)e * 4);
  const float cbe = cbp[e];
  const int l0 = c * CHT_;
  float p0 = (l0 >= 3) ? bf2f(xu[((size_t)b * L_ + l0 - 3) * DI_ + e]) : 0.f;
  float p1 = (l0 >= 2) ? bf2f(xu[((size_t)b * L_ + l0 - 2) * DI_ + e]) : 0.f;
  float p2 = (l0 >= 1) ? bf2f(xu[((size_t)b * L_ + l0 - 1) * DI_ + e]) : 0.f;
  float h[DS_];
#pragma unroll
  for (int s = 0; s < DS_; s++) h[s] = 0.f;
  float sdd = 0.f;
  const size_t base = ((size_t)b * L_ + l0) * DI_ + e;
  for (int t = 0; t < CHT_; t++){
    float up = bf2f(xu[base + (size_t)t * DI_]);
    float a = cbe + cwv.x * p0 + cwv.y * p1 + cwv.z * p2 + cwv.w * up;
    p0 = p1; p1 = p2; p2 = up;
    float ut = siluf(a);
    const float* r = &DT[t][0];
    float dp = dtbe;
#pragma unroll
    for (int q = 0; q < 8; q++){
      float4 x4 = *(const float4*)(r + q * 4);
      dp += x4.x * dw[q*4] + x4.y * dw[q*4+1] + x4.z * dw[q*4+2] + x4.w * dw[q*4+3];
    }
    float delta = (dp > 20.f) ? dp : log1pf(__expf(dp));
    sdd += delta;
    float du = delta * ut;
    float4 B0 = *(const float4*)(r + 32);
    float4 B1 = *(const float4*)(r + 36);
    float4 B2 = *(const float4*)(r + 40);
    float4 B3 = *(const float4*)(r + 44);
    float Bv[16] = {B0.x,B0.y,B0.z,B0.w, B1.x,B1.y,B1.z,B1.w,
                    B2.x,B2.y,B2.z,B2.w, B3.x,B3.y,B3.z,B3.w};
#pragma unroll
    for (int s = 0; s < DS_; s++)
      h[s] = __expf(delta * As[s]) * h[s] + du * Bv[s];
  }
  float* p = sb + ((size_t)c * (B_ * DI_) + (size_t)b * DI_ + e) * 32;
#pragma unroll
  for (int s = 0; s < DS_; s++) p[s] = __expf(As[s] * sdd);
#pragma unroll
  for (int s = 0; s < DS_; s++) p[16 + s] = h[s];
}

// ---------------- scan pass 2: combine chunk summaries -> h_init per chunk --------
__global__ __launch_bounds__(256)
void scan2_kernel(float* __restrict__ sb){
  const int be = blockIdx.x * 256 + threadIdx.x;
  const int BE = B_ * DI_;
  float h[DS_];
#pragma unroll
  for (int s = 0; s < DS_; s++) h[s] = 0.f;
  for (int c = 0; c < NCH_; c++){
    float* p = sb + ((size_t)c * BE + be) * 32;
    float4 a0 = *(const float4*)(p);
    float4 a1 = *(const float4*)(p + 4);
    float4 a2 = *(const float4*)(p + 8);
    float4 a3 = *(const float4*)(p + 12);
    float4 h0 = *(const float4*)(p + 16);
    float4 h1 = *(const float4*)(p + 20);
    float4 h2 = *(const float4*)(p + 24);
    float4 h3 = *(const float4*)(p + 28);
    float av[16] = {a0.x,a0.y,a0.z,a0.w, a1.x,a1.y,a1.z,a1.w,
                    a2.x,a2.y,a2.z,a2.w, a3.x,a3.y,a3.z,a3.w};
    float hv[16] = {h0.x,h0.y,h0.z,h0.w, h1.x,h1.y,h1.z,h1.w,
                    h2.x,h2.y,h2.z,h2.w, h3.x,h3.y,h3.z,h3.w};
    float4 w0, w1, w2, w3;
    float* wv[4] = {&w0.x, &w1.x, &w2.x, &w3.x};
#pragma unroll
    for (int s = 0; s < DS_; s++){
      float hi = h[s];
      h[s] = av[s] * hi + hv[s];
      wv[s >> 2][s & 3] = hi;
    }
    *(float4*)(p + 16) = w0;
    *(float4*)(p + 20) = w1;
    *(float4*)(p + 24) = w2;
    *(float4*)(p + 28) = w3;
  }
}

// ---------------- scan pass 3: fused conv+dt+gate; y over silu(z) in place --------
__global__ __launch_bounds__(256)
void scan3_kernel(const u16* __restrict__ xu, u16* __restrict__ zy,
                  const u16* __restrict__ xdb,
                  const float* __restrict__ dtw, const float* __restrict__ dtb,
                  const float* __restrict__ cwp, const float* __restrict__ cbp,
                  const float* __restrict__ A_log, const float* __restrict__ Dp,
                  const float* __restrict__ sb){
  const int tid = threadIdx.x;
  const int e = blockIdx.x * 256 + tid;
  const int c = blockIdx.y, b = blockIdx.z;
  __shared__ float DT[CHT_][64];                 // 32 KB: dt | B | C
  {
    int row = tid >> 1, half = (tid & 1) * 32;
    const u16* p = xdb + ((size_t)b * L_ + (size_t)c * CHT_ + row) * 64 + half;
#pragma unroll
    for (int q = 0; q < 8; q++){
      ushort4 v = *(const ushort4*)(p + q * 4);
      DT[row][half + q*4 + 0] = bf2f(v.x);
      DT[row][half + q*4 + 1] = bf2f(v.y);
      DT[row][half + q*4 + 2] = bf2f(v.z);
      DT[row][half + q*4 + 3] = bf2f(v.w);
    }
  }
  __syncthreads();
  float As[DS_];
#pragma unroll
  for (int s = 0; s < DS_; s++) As[s] = -__expf(A_log[e * DS_ + s]);
  float dw[32];
#pragma unroll
  for (int q = 0; q < 8; q++){
    float4 w4 = *(const float4*)(dtw + (size_t)e * DTR_ + q * 4);
    dw[q*4]=w4.x; dw[q*4+1]=w4.y; dw[q*4+2]=w4.z; dw[q*4+3]=w4.w;
  }
  const float dtbe = dtb[e];
  const float4 cwv = *(const float4*)(cwp + (size_t)e * 4);
  const float cbe = cbp[e];
  const float Dv = Dp[e];
  const int l0 = c * CHT_;
  float p0 = (l0 >= 3) ? bf2f(xu[((size_t)b * L_ + l0 - 3) * DI_ + e]) : 0.f;
  float p1 = (l0 >= 2) ? bf2f(xu[((size_t)b * L_ + l0 - 2) * DI_ + e]) : 0.f;
  float p2 = (l0 >= 1) ? bf2f(xu[((size_t)b * L_ + l0 - 1) * DI_ + e]) : 0.f;
  const float* ip = sb + ((size_t)c * (B_ * DI_) + (size_t)b * DI_ + e) * 32 + 16;
  float h[DS_];
#pragma unroll
  for (int s = 0; s < DS_; s++) h[s] = ip[s];
  const size_t base = ((size_t)b * L_ + l0) * DI_ + e;
  for (int t = 0; t < CHT_; t++){
    const size_t idx = base + (size_t)t * DI_;
    float up = bf2f(xu[idx]);
    float a = cbe + cwv.x * p0 + cwv.y * p1 + cwv.z * p2 + cwv.w * up;
    p0 = p1; p1 = p2; p2 = up;
    float ut = siluf(a);
    const float* r = &DT[t][0];
    float dp = dtbe;
#pragma unroll
    for (int q = 0; q < 8; q++){
      float4 x4 = *(const float4*)(r + q * 4);
      dp += x4.x * dw[q*4] + x4.y * dw[q*4+1] + x4.z * dw[q*4+2] + x4.w * dw[q*4+3];
    }
    float delta = (dp > 20.f) ? dp : log1pf(__expf(dp));
    float du = delta * ut;
    float4 B0 = *(const float4*)(r + 32);
    float4 B1 = *(const float4*)(r + 36);
    float4 B2 = *(const float4*)(r + 40);
    float4 B3 = *(const float4*)(r + 44);
    float4 C0 = *(const float4*)(r + 48);
    float4 C1 = *(const float4*)(r + 52);
    float4 C2 = *(const float4*)(r + 56);
    float4 C3 = *(const float4*)(r + 60);
    float Bv[16] = {B0.x,B0.y,B0.z,B0.w, B1.x,B1.y,B1.z,B1.w,
                    B2.x,B2.y,B2.z,B2.w, B3.x,B3.y,B3.z,B3.w};
    float Cv[16] = {C0.x,C0.y,C0.z,C0.w, C1.x,C1.y,C1.z,C1.w,
                    C2.x,C2.y,C2.z,C2.w, C3.x,C3.y,C3.z,C3.w};
    float yv = 0.f;
#pragma unroll
    for (int s = 0; s < DS_; s++){
      h[s] = __expf(delta * As[s]) * h[s] + du * Bv[s];
      yv += h[s] * Cv[s];
    }
    float zs = bf2f(zy[idx]);                    // silu(z), precomputed by GEMM epi
    zy[idx] = f2bf((yv + ut * Dv) * zs);
  }
}

// ---------------- mean-pool partials over L (bf16 h) ----------------
__global__ __launch_bounds__(256) void pool_kernel(const u16* __restrict__ h,
                                                   float* __restrict__ part){
  int d = blockIdx.x * 256 + threadIdx.x;
  int b = blockIdx.y;
  int p = blockIdx.z;
  float s = 0.f;
  const u16* hp = h + ((size_t)b * L_ + p * 128) * DM_ + d;
  for (int l = 0; l < 128; l++) s += bf2f(hp[(size_t)l * DM_]);
  part[((size_t)p * B_ + b) * DM_ + d] = s;
}

// ---------------- final FC ----------------
__global__ __launch_bounds__(256) void fc_kernel(const float* __restrict__ part,
                                                 const float* __restrict__ fcw,
                                                 const float* __restrict__ fcb,
                                                 float* __restrict__ out){
  int b = blockIdx.x;
  int tid = threadIdx.x;
  __shared__ float pd[DM_];
  for (int d = tid; d < DM_; d += 256){
    float s = 0.f;
    for (int p = 0; p < 8; p++) s += part[((size_t)p * B_ + b) * DM_ + d];
    pd[d] = s * (1.f / L_);
  }
  __syncthreads();
  int wid = tid >> 6, lane = tid & 63;
  for (int c = wid; c < NC_; c += 4){
    float s = 0.f;
    for (int d = lane; d < DM_; d += 64) s += pd[d] * fcw[c * DM_ + d];
#pragma unroll
    for (int o = 32; o; o >>= 1) s += __shfl_xor(s, o);
    if (lane == 0) out[b * NC_ + c] = s + fcb[c];
  }
}

extern "C" void kernel_launch(void* const* d_in, const int* in_sizes, int n_in,
                              void* d_out, int out_size, void* d_ws, size_t ws_size,
                              hipStream_t stream){
  const float* x     = (const float*)d_in[0];
  const float* ip_w  = (const float*)d_in[1];
  const float* ip_b  = (const float*)d_in[2];
  const float* ln_g  = (const float*)d_in[3];
  const float* ln_b  = (const float*)d_in[4];
  const float* inpw  = (const float*)d_in[5];
  const float* convw = (const float*)d_in[6];
  const float* convb = (const float*)d_in[7];
  const float* xpw   = (const float*)d_in[8];
  const float* dtw   = (const float*)d_in[9];
  const float* dtb   = (const float*)d_in[10];
  const float* Alog  = (const float*)d_in[11];
  const float* Dp    = (const float*)d_in[12];
  const float* outw  = (const float*)d_in[13];
  const float* fcw   = (const float*)d_in[14];
  const float* fcb   = (const float*)d_in[15];
  float* out = (float*)d_out;

  char* ws = (char*)d_ws;
  size_t off = 0;
  auto alloc = [&](size_t bytes) -> void* {
    void* p = ws + off; off += (bytes + 255) & ~(size_t)255; return p;
  };
  // total footprint ~212 MB (ws_size >= ~238 MB established in round 3)
  u16*    h16   = (u16*)   alloc((size_t)M_ * DM_ * 2);      // 32 MB residual stream
  float*  part  = (float*) alloc((size_t)8 * B_ * DM_ * 4);  // 0.5 MB
  u16*    w_in  = (u16*)   alloc((size_t)NW1_ * 2);          // 8.4 MB
  u16*    w_xp  = (u16*)   alloc((size_t)NW2_ * 2);          // 0.5 MB
  u16*    w_out = (u16*)   alloc((size_t)NW3_ * 2);          // 4.2 MB
  float2* stats = (float2*)alloc((size_t)M_ * 8);            // 0.25 MB
  u16*    xu    = (u16*)   alloc((size_t)M_ * DI_ * 2);      // 64 MB u_pre
  u16*    xzs   = (u16*)   alloc((size_t)M_ * DI_ * 2);      // 64 MB silu(z) -> y
  u16*    xdb   = (u16*)   alloc((size_t)M_ * 64 * 2);       // 4 MB x_dbl
  float*  sb    = (float*) alloc((size_t)NCH_ * B_ * DI_ * 32 * 4);  // 33.5 MB

  cast3_kernel<<<(NW1_ + NW2_ + NW3_ + 255) / 256, 256, 0, stream>>>(
      inpw, xpw, outw, w_in, w_xp, w_out);

  inproj_kernel<<<M_, 512, 0, stream>>>(x, ip_w, ip_b, h16);

  for (int i = 0; i < NL_; i++){
    lnstats_kernel<<<M_ / 4, 256, 0, stream>>>(h16, stats);

    // in-proj with fused LN staging; split epilogue: xu = u_pre, xzs = silu(z)
    gemm_bt<128, 128, 64, 4, 1><<<dim3(2 * DI_ / 128, M_ / 128), 256, 0, stream>>>(
        h16, DM_, w_in + (size_t)i * 2 * DI_ * DM_, xu, xzs, nullptr,
        stats, ln_g + i * DM_, ln_b + i * DM_, nullptr, nullptr,
        2 * DI_, DM_, DI_);

    // x_dbl = silu(conv(u_pre)) @ x_proj^T, conv+silu fused into A staging
    gemm_bt<128, 64, 64, 0, 2><<<dim3(1, M_ / 128), 256, 0, stream>>>(
        xu, DI_, w_xp + (size_t)i * 64 * DI_, xdb, nullptr, nullptr,
        nullptr, nullptr, nullptr, convw + i * DI_ * DC_, convb + i * DI_,
        64, DI_, 0);

    // chunk-parallel scan with fused conv+dt (+gate in pass 3)
    scan1_kernel<<<dim3(DI_ / 256, NCH_, B_), 256, 0, stream>>>(
        xu, xdb, dtw + (size_t)i * DI_ * DTR_, dtb + i * DI_,
        convw + i * DI_ * DC_, convb + i * DI_,
        Alog + (size_t)i * DI_ * DS_, sb);
    scan2_kernel<<<(B_ * DI_) / 256, 256, 0, stream>>>(sb);
    scan3_kernel<<<dim3(DI_ / 256, NCH_, B_), 256, 0, stream>>>(
        xu, xzs, xdb, dtw + (size_t)i * DI_ * DTR_, dtb + i * DI_,
        convw + i * DI_ * DC_, convb + i * DI_,
        Alog + (size_t)i * DI_ * DS_, Dp + i * DI_, sb);

    // h += y_gated @ out_w^T
    gemm_bt<128, 128, 64, 2, 0><<<dim3(DM_ / 128, M_ / 128), 256, 0, stream>>>(
        xzs, DI_, w_out + (size_t)i * DM_ * DI_, h16, nullptr, h16,
        nullptr, nullptr, nullptr, nullptr, nullptr,
        DM_, DI_, 0);
  }

  pool_kernel<<<dim3(2, B_, 8), 256, 0, stream>>>(h16, part);
  fc_kernel<<<B_, 256, 0, stream>>>(part, fcw, fcb, out);
}